// Round 2
// baseline (310.667 us; speedup 1.0000x reference)
//
#include <hip/hip_runtime.h>

// MobileMQA: the reference's softmax is over a size-1 axis -> attn == 1,
// Q/K are dead. Reduces to:
//   Wv[c][d] = mean_h W_qkv[c][1024 + h*64 + d];  bv[d] = mean_h b_qkv[1024+h*64+d]
//   V[b,n,d] = sum_c x[b,c,n]*Wv[c,d] + bv[d]          (GEMM1: 32768x64, K=512)
//   Z[b]     = V[b] viewed as (128, 512)               (exact reshape: n*64+d = j*512+c)
//   P[b]     = Z[b] @ W_proj + b_proj                  (GEMM2: 128x512 per batch)
//   out[b,c',i] = P[b, i % 128, c']                    (8x replicated write, i = rr*128 + j)

#define CC 512
#define NN 1024
#define HD 64

__global__ __launch_bounds__(256) void prep_kernel(
    const float* __restrict__ Wqkv, const float* __restrict__ bqkv,
    float* __restrict__ Wv, float* __restrict__ bv) {
  int t = blockIdx.x * 256 + threadIdx.x;  // 0..32767
  int c = t >> 6, d = t & 63;
  float s = 0.f;
#pragma unroll
  for (int h = 0; h < 8; ++h) s += Wqkv[c * 1536 + 1024 + h * 64 + d];
  Wv[t] = s * 0.125f;
  if (t < 64) {
    float sb = 0.f;
#pragma unroll
    for (int h = 0; h < 8; ++h) sb += bqkv[1024 + h * 64 + d];
    bv[d] = sb * 0.125f;
  }
}

// GEMM1: grid (16 n-chunks, 32 b), block 256.
// thread: nloc = t&63 (n within chunk), dq = t>>6 (wave-uniform d-quarter).
__global__ __launch_bounds__(256) void gemm1_kernel(
    const float* __restrict__ x, const float* __restrict__ Wv,
    const float* __restrict__ bv, float* __restrict__ V) {
  const int b = blockIdx.y;
  const int nloc = (int)(threadIdx.x & 63);
  const int dq = (int)(threadIdx.x >> 6);  // 0..3, wave-uniform
  const int n = blockIdx.x * 64 + nloc;
  const float* xp = x + (size_t)b * (CC * NN) + n;
  const float4* wp = (const float4*)Wv + dq * 4;  // +c*16 walks rows of Wv
  float acc[16];
#pragma unroll
  for (int i = 0; i < 16; ++i) acc[i] = 0.f;
#pragma unroll 4
  for (int c = 0; c < CC; ++c) {
    const float xv = xp[(size_t)c * NN];
    const float4 w0 = wp[c * 16 + 0];
    const float4 w1 = wp[c * 16 + 1];
    const float4 w2 = wp[c * 16 + 2];
    const float4 w3 = wp[c * 16 + 3];
    acc[0]  += xv * w0.x; acc[1]  += xv * w0.y; acc[2]  += xv * w0.z; acc[3]  += xv * w0.w;
    acc[4]  += xv * w1.x; acc[5]  += xv * w1.y; acc[6]  += xv * w1.z; acc[7]  += xv * w1.w;
    acc[8]  += xv * w2.x; acc[9]  += xv * w2.y; acc[10] += xv * w2.z; acc[11] += xv * w2.w;
    acc[12] += xv * w3.x; acc[13] += xv * w3.y; acc[14] += xv * w3.z; acc[15] += xv * w3.w;
  }
  const float4 b0 = ((const float4*)bv)[dq * 4 + 0];
  const float4 b1 = ((const float4*)bv)[dq * 4 + 1];
  const float4 b2 = ((const float4*)bv)[dq * 4 + 2];
  const float4 b3 = ((const float4*)bv)[dq * 4 + 3];
  float4* vp = (float4*)(V + ((size_t)b * NN + n) * HD + dq * 16);
  vp[0] = make_float4(acc[0] + b0.x, acc[1] + b0.y, acc[2] + b0.z, acc[3] + b0.w);
  vp[1] = make_float4(acc[4] + b1.x, acc[5] + b1.y, acc[6] + b1.z, acc[7] + b1.w);
  vp[2] = make_float4(acc[8] + b2.x, acc[9] + b2.y, acc[10] + b2.z, acc[11] + b2.w);
  vp[3] = make_float4(acc[12] + b3.x, acc[13] + b3.y, acc[14] + b3.z, acc[15] + b3.w);
}

// GEMM2 + fused replicated output write.
// grid (8 c'-tiles, 32 b, 2 j-tiles), block 128. Tile: 64 j x 64 c', K-chunks of 64.
// NOTE: Z[b] has 128 rows -> exactly 2 j-tiles. (grid.z=4 was the round-1 OOB crash.)
// Each block writes its P-tile 8x replicated: out col i = rr*128 + jt*64 + jloc, rr in [0,8).
__global__ __launch_bounds__(128) void gemm2_kernel(
    const float* __restrict__ V, const float* __restrict__ Wproj,
    const float* __restrict__ bproj, float* __restrict__ out) {
  __shared__ float Zl[64][65];
  __shared__ float Wl[64][64];
  const int ct = blockIdx.x;  // 0..7
  const int b  = blockIdx.y;  // 0..31
  const int jt = blockIdx.z;  // 0..1
  const int t = (int)threadIdx.x;
  const int cg = t & 7;
  const int jg = t >> 3;  // 0..15
  const float* Zb = V + (size_t)b * (128 * 512) + (size_t)jt * 64 * 512;
  float acc[4][8];
#pragma unroll
  for (int r = 0; r < 4; ++r)
#pragma unroll
    for (int e = 0; e < 8; ++e) acc[r][e] = 0.f;

  for (int kc = 0; kc < 512; kc += 64) {
    // stage Z[jt*64 : +64, kc : kc+64] and W_proj[kc : kc+64, ct*64 : +64]
#pragma unroll
    for (int k = 0; k < 8; ++k) {
      int f = t + 128 * k;  // 0..1023
      int row = f >> 4, pos = f & 15;
      float4 v = *(const float4*)(Zb + row * 512 + kc + pos * 4);
      Zl[row][pos * 4 + 0] = v.x;
      Zl[row][pos * 4 + 1] = v.y;
      Zl[row][pos * 4 + 2] = v.z;
      Zl[row][pos * 4 + 3] = v.w;
      float4 w = *(const float4*)(Wproj + (size_t)(kc + row) * 512 + ct * 64 + pos * 4);
      *(float4*)&Wl[row][pos * 4] = w;
    }
    __syncthreads();
#pragma unroll 2
    for (int cl = 0; cl < 64; ++cl) {
      const float4 wa = *(const float4*)&Wl[cl][cg * 8];
      const float4 wb = *(const float4*)&Wl[cl][cg * 8 + 4];
      float zv[4];
#pragma unroll
      for (int r = 0; r < 4; ++r) zv[r] = Zl[jg * 4 + r][cl];
#pragma unroll
      for (int r = 0; r < 4; ++r) {
        acc[r][0] += zv[r] * wa.x; acc[r][1] += zv[r] * wa.y;
        acc[r][2] += zv[r] * wa.z; acc[r][3] += zv[r] * wa.w;
        acc[r][4] += zv[r] * wb.x; acc[r][5] += zv[r] * wb.y;
        acc[r][6] += zv[r] * wb.z; acc[r][7] += zv[r] * wb.w;
      }
    }
    __syncthreads();
  }
  // P tile (+ b_proj) into LDS (reuse Zl), then coalesced replicated write.
#pragma unroll
  for (int e = 0; e < 8; ++e) {
    const float bp = bproj[ct * 64 + cg * 8 + e];
#pragma unroll
    for (int r = 0; r < 4; ++r) Zl[jg * 4 + r][cg * 8 + e] = acc[r][e] + bp;
  }
  __syncthreads();
  // out[b, ct*64+cl, rr*128 + jt*64 + j4+q] = P[j4+q, cl];  8192 float4 per block
  float* ob = out + ((size_t)b * 512 + ct * 64) * 1024 + jt * 64;
#pragma unroll 4
  for (int k = 0; k < 64; ++k) {
    int F = t + 128 * k;      // 0..8191
    int cl = F >> 7;          // 0..63
    int rem = F & 127;
    int rr = rem >> 4;        // 0..7 replication index
    int j4 = (rem & 15) * 4;  // 0..60
    float4 v;
    v.x = Zl[j4 + 0][cl];
    v.y = Zl[j4 + 1][cl];
    v.z = Zl[j4 + 2][cl];
    v.w = Zl[j4 + 3][cl];
    *(float4*)(ob + (size_t)cl * 1024 + rr * 128 + j4) = v;
  }
}

extern "C" void kernel_launch(void* const* d_in, const int* in_sizes, int n_in,
                              void* d_out, int out_size, void* d_ws, size_t ws_size,
                              hipStream_t stream) {
  (void)in_sizes; (void)n_in; (void)out_size; (void)ws_size;
  const float* x     = (const float*)d_in[0];
  const float* Wqkv  = (const float*)d_in[1];
  const float* bqkv  = (const float*)d_in[2];
  const float* Wproj = (const float*)d_in[3];
  const float* bproj = (const float*)d_in[4];
  float* out = (float*)d_out;
  float* ws  = (float*)d_ws;
  float* Wv = ws;             // 512*64 = 32768 floats
  float* bv = ws + 32768;     // 64 floats
  float* V  = ws + 32832;     // 32*1024*64 = 2097152 floats (16B-aligned offset)

  prep_kernel<<<128, 256, 0, stream>>>(Wqkv, bqkv, Wv, bv);
  gemm1_kernel<<<dim3(16, 32), 256, 0, stream>>>(x, Wv, bv, V);
  gemm2_kernel<<<dim3(8, 32, 2), 128, 0, stream>>>(V, Wproj, bproj, out);
}

// Round 3
// 195.948 us; speedup vs baseline: 1.5855x; 1.5855x over previous
//
#include <hip/hip_runtime.h>

// MobileMQA reduction (softmax over size-1 axis == 1; Q/K dead):
//   Wv[c][d] = mean_h W_qkv[c][1024+h*64+d]; bv likewise       (prep)
//   V[b,n,d] = sum_c x[b,c,n]*Wv[c,d] + bv[d]                  (gemm1: M=1024/b, N=64, K=512)
//   Z[b] = V[b].reshape(128,512)  (exact: n*64+d == j*512+c)
//   P[b] = Z[b] @ W_proj + b_proj                              (gemm2: M=128/b, N=512, K=512)
//   out[b,c',i] = P[b, i&127, c']                              (8x replication, fused in gemm2 epilogue)

typedef unsigned int u32;

__device__ __forceinline__ void gll16(const float* g, float* l) {
  __builtin_amdgcn_global_load_lds(
      (const __attribute__((address_space(1))) u32*)g,
      (__attribute__((address_space(3))) u32*)l, 16, 0, 0);
}

__global__ __launch_bounds__(256) void prep_kernel(
    const float* __restrict__ Wqkv, const float* __restrict__ bqkv,
    float* __restrict__ Wv, float* __restrict__ bv) {
  int t = blockIdx.x * 256 + threadIdx.x;  // 0..32767
  int c = t >> 6, d = t & 63;
  float s = 0.f;
#pragma unroll
  for (int h = 0; h < 8; ++h) s += Wqkv[c * 1536 + 1024 + h * 64 + d];
  Wv[t] = s * 0.125f;
  if (t < 64) {
    float sb = 0.f;
#pragma unroll
    for (int h = 0; h < 8; ++h) sb += bqkv[1024 + h * 64 + d];
    bv[d] = sb * 0.125f;
  }
}

// gemm1: grid (16 nt, 32 b), 256 thr. Block tile 64n x 64d, 4x4/thread, BK=32.
// Double-buffered LDS via global_load_lds (linear layout; X compute-read is
// 4-address broadcast, W read 256B-contiguous -> conflict-free unpadded).
__global__ __launch_bounds__(256) void gemm1_kernel(
    const float* __restrict__ x, const float* __restrict__ Wv,
    const float* __restrict__ bv, float* __restrict__ V) {
  __shared__ float Xl[2][2048];  // [c<32][n<64]
  __shared__ float Wl[2][2048];  // [c<32][d<64]
  const int nt = blockIdx.x, b = blockIdx.y;
  const int t = (int)threadIdx.x;
  const int w = t >> 6;
  const int ng = t >> 4;  // 0..15 (n group)
  const int dg = t & 15;  // 0..15 (d group)
  const int f0 = t, f1 = t + 256;  // staging float4 slots (c = f>>4, n4 = f&15)
  const float* xg0 = x + (size_t)b * 524288 + (size_t)(f0 >> 4) * 1024 + nt * 64 + (f0 & 15) * 4;
  const float* xg1 = x + (size_t)b * 524288 + (size_t)(f1 >> 4) * 1024 + nt * 64 + (f1 & 15) * 4;
  const float* wg0 = Wv + (f0 >> 4) * 64 + (f0 & 15) * 4;
  const float* wg1 = Wv + (f1 >> 4) * 64 + (f1 & 15) * 4;

  float acc[4][4] = {};

#define G1_STAGE(buf, ch)                                   \
  do {                                                      \
    const size_t xo = (size_t)(ch) * 32768;                 \
    const int wo = (ch) * 2048;                             \
    gll16(xg0 + xo, &Xl[buf][w * 256]);                     \
    gll16(xg1 + xo, &Xl[buf][w * 256 + 1024]);              \
    gll16(wg0 + wo, &Wl[buf][w * 256]);                     \
    gll16(wg1 + wo, &Wl[buf][w * 256 + 1024]);              \
  } while (0)

  G1_STAGE(0, 0);
  __syncthreads();
  int cur = 0;
  for (int ch = 0; ch < 16; ++ch) {
    if (ch < 15) G1_STAGE(cur ^ 1, ch + 1);
    const float* Xb = &Xl[cur][ng * 4];
    const float* Wb = &Wl[cur][dg * 4];
#pragma unroll 8
    for (int c = 0; c < 32; ++c) {
      const float4 xa = *(const float4*)(Xb + c * 64);
      const float4 wa = *(const float4*)(Wb + c * 64);
      acc[0][0] += xa.x * wa.x; acc[0][1] += xa.x * wa.y; acc[0][2] += xa.x * wa.z; acc[0][3] += xa.x * wa.w;
      acc[1][0] += xa.y * wa.x; acc[1][1] += xa.y * wa.y; acc[1][2] += xa.y * wa.z; acc[1][3] += xa.y * wa.w;
      acc[2][0] += xa.z * wa.x; acc[2][1] += xa.z * wa.y; acc[2][2] += xa.z * wa.z; acc[2][3] += xa.z * wa.w;
      acc[3][0] += xa.w * wa.x; acc[3][1] += xa.w * wa.y; acc[3][2] += xa.w * wa.z; acc[3][3] += xa.w * wa.w;
    }
    __syncthreads();
    cur ^= 1;
  }
#undef G1_STAGE

  const int n = nt * 64 + ng * 4;
  const float4 bb = *(const float4*)(bv + dg * 4);
  float* vp = V + ((size_t)b * 1024 + n) * 64 + dg * 4;
#pragma unroll
  for (int r = 0; r < 4; ++r) {
    float4 o;
    o.x = acc[r][0] + bb.x; o.y = acc[r][1] + bb.y;
    o.z = acc[r][2] + bb.z; o.w = acc[r][3] + bb.w;
    *(float4*)(vp + (size_t)r * 64) = o;
  }
}

// gemm2 + fused 8x-replicated write. grid (16 ct, 32 b), 256 thr.
// Block tile 128j x 32c' (block owns FULL output rows -> contiguous stores).
// 4x4/thread (jg = t>>3 in 0..31, cg = t&7), BK=32.
// Z reg-staged into stride-33 LDS (issue-early / write-late); W via global_load_lds.
__global__ __launch_bounds__(256) void gemm2_kernel(
    const float* __restrict__ V, const float* __restrict__ Wproj,
    const float* __restrict__ bproj, float* __restrict__ out) {
  __shared__ float Zl[2][4224];  // [j<128] stride 33
  __shared__ float Wl[2][1024];  // [k<32][c<32]
  const int ct = blockIdx.x, b = blockIdx.y;
  const int t = (int)threadIdx.x;
  const int w = t >> 6;
  const int jg = t >> 3;  // 0..31
  const int cg = t & 7;   // 0..7
  const float* zg = V + (size_t)b * 65536;
  const float* wg = Wproj + (size_t)(t >> 3) * 512 + ct * 32 + (t & 7) * 4;

  float4 zr[4];
  float acc[4][4] = {};

#define Z_LOAD(ch)                                                              \
  do {                                                                          \
    _Pragma("unroll") for (int kk = 0; kk < 4; ++kk) {                          \
      int f = t + 256 * kk;                                                     \
      zr[kk] = *(const float4*)(zg + (size_t)(f >> 3) * 512 + (ch) * 32 + (f & 7) * 4); \
    }                                                                           \
  } while (0)
#define Z_WRITE(buf)                                                            \
  do {                                                                          \
    _Pragma("unroll") for (int kk = 0; kk < 4; ++kk) {                          \
      int f = t + 256 * kk;                                                     \
      float* p = &Zl[buf][(f >> 3) * 33 + (f & 7) * 4];                         \
      p[0] = zr[kk].x; p[1] = zr[kk].y; p[2] = zr[kk].z; p[3] = zr[kk].w;       \
    }                                                                           \
  } while (0)

  Z_LOAD(0);
  gll16(wg, &Wl[0][w * 256]);
  Z_WRITE(0);
  __syncthreads();
  int cur = 0;
  for (int ch = 0; ch < 16; ++ch) {
    if (ch < 15) {
      Z_LOAD(ch + 1);
      gll16(wg + (size_t)(ch + 1) * 16384, &Wl[cur ^ 1][w * 256]);
    }
    const float* Zb = &Zl[cur][jg * 132];  // (jg*4)*33
    const float* Wb = &Wl[cur][cg * 4];
#pragma unroll 4
    for (int k = 0; k < 32; ++k) {
      const float4 wa = *(const float4*)(Wb + k * 32);
      const float z0 = Zb[k], z1 = Zb[33 + k], z2 = Zb[66 + k], z3 = Zb[99 + k];
      acc[0][0] += z0 * wa.x; acc[0][1] += z0 * wa.y; acc[0][2] += z0 * wa.z; acc[0][3] += z0 * wa.w;
      acc[1][0] += z1 * wa.x; acc[1][1] += z1 * wa.y; acc[1][2] += z1 * wa.z; acc[1][3] += z1 * wa.w;
      acc[2][0] += z2 * wa.x; acc[2][1] += z2 * wa.y; acc[2][2] += z2 * wa.z; acc[2][3] += z2 * wa.w;
      acc[3][0] += z3 * wa.x; acc[3][1] += z3 * wa.y; acc[3][2] += z3 * wa.z; acc[3][3] += z3 * wa.w;
    }
    if (ch < 15) Z_WRITE(cur ^ 1);
    __syncthreads();
    cur ^= 1;
  }
#undef Z_LOAD
#undef Z_WRITE

  // Epilogue: P tile (+bias) -> LDS (stride 33), then fully-coalesced
  // replicated stores: row c' gets 8 copies of P[:,c'] (1024B contiguous per wave).
  float* Pl = &Zl[0][0];
#pragma unroll
  for (int e = 0; e < 4; ++e) {
    const float bp = bproj[ct * 32 + cg * 4 + e];
#pragma unroll
    for (int i = 0; i < 4; ++i)
      Pl[(jg * 4 + i) * 33 + cg * 4 + e] = acc[i][e] + bp;
  }
  __syncthreads();
  float* ob = out + ((size_t)b * 512 + ct * 32) * 1024;
  const int jj = (t * 4) & 127;  // j for this lane's float4 (same for every row)
  const float* Pj = &Pl[jj * 33];
#pragma unroll 8
  for (int c = 0; c < 32; ++c) {
    float4 v;
    v.x = Pj[c];
    v.y = Pj[33 + c];
    v.z = Pj[66 + c];
    v.w = Pj[99 + c];
    *(float4*)(ob + (size_t)c * 1024 + t * 4) = v;
  }
}

extern "C" void kernel_launch(void* const* d_in, const int* in_sizes, int n_in,
                              void* d_out, int out_size, void* d_ws, size_t ws_size,
                              hipStream_t stream) {
  (void)in_sizes; (void)n_in; (void)out_size; (void)ws_size;
  const float* x     = (const float*)d_in[0];
  const float* Wqkv  = (const float*)d_in[1];
  const float* bqkv  = (const float*)d_in[2];
  const float* Wproj = (const float*)d_in[3];
  const float* bproj = (const float*)d_in[4];
  float* out = (float*)d_out;
  float* ws  = (float*)d_ws;
  float* Wv = ws;            // 512*64
  float* bv = ws + 32768;    // 64
  float* V  = ws + 32832;    // 32*1024*64

  prep_kernel<<<128, 256, 0, stream>>>(Wqkv, bqkv, Wv, bv);
  gemm1_kernel<<<dim3(16, 32), 256, 0, stream>>>(x, Wv, bv, V);
  gemm2_kernel<<<dim3(16, 32), 256, 0, stream>>>(V, Wproj, bproj, out);
}

// Round 4
// 142.759 us; speedup vs baseline: 2.1762x; 1.3726x over previous
//
#include <hip/hip_runtime.h>
#include <hip/hip_bf16.h>

// MobileMQA reduction (softmax over size-1 axis == 1; Q/K dead):
//   Wvt[d][c] = mean_h W_qkv[c][1024+h*64+d] (bf16), bv[d] likewise (f32)
//   V[b,n,d]  = sum_c x[b,c,n]*Wvt[d][c] + bv[d]     (gemm1, MFMA bf16, V stored bf16)
//   Z[b] = V[b] viewed (128,512); P[b] = Z[b]@Wproj + bproj   (gemm2, MFMA bf16)
//   out[b,c',i] = P[b, i&127, c']  fp32                (8x replication in gemm2 epilogue)

typedef unsigned int u32;
typedef __attribute__((ext_vector_type(8))) short short8;  // 8 bf16 = 4 VGPR MFMA frag
typedef __attribute__((ext_vector_type(4))) float f32x4;

__device__ __forceinline__ void gll16(const void* g, void* l) {
  __builtin_amdgcn_global_load_lds(
      (const __attribute__((address_space(1))) u32*)g,
      (__attribute__((address_space(3))) u32*)l, 16, 0, 0);
}
__device__ __forceinline__ u32 packbf2(float a, float b) {
  __hip_bfloat162 p = __float22bfloat162_rn(make_float2(a, b));
  return *(u32*)&p;
}

// blocks 0..255: Wproj 32x32 tile transpose -> Wpt bf16. blocks 256..383: Wvt + bv.
__global__ __launch_bounds__(256) void prep_kernel(
    const float* __restrict__ Wqkv, const float* __restrict__ bqkv,
    const float* __restrict__ Wproj, __hip_bfloat16* __restrict__ Wvt,
    float* __restrict__ bv, __hip_bfloat16* __restrict__ Wpt) {
  const int bid = blockIdx.x, t = (int)threadIdx.x;
  if (bid < 256) {
    __shared__ float Tl[32][33];
    const int tr = bid >> 4, tc = bid & 15;  // c-tile, cp-tile
    const int c0 = tr * 32, p0 = tc * 32;
    const int r = t >> 5, col = t & 31;
#pragma unroll
    for (int a = 0; a < 4; ++a)
      Tl[r + a * 8][col] = Wproj[(size_t)(c0 + r + a * 8) * 512 + p0 + col];
    __syncthreads();
#pragma unroll
    for (int a = 0; a < 4; ++a)  // Wpt[p0+row][c0+col] = Wproj[c0+col][p0+row]
      Wpt[(size_t)(p0 + r + a * 8) * 512 + c0 + col] = __float2bfloat16(Tl[col][r + a * 8]);
  } else {
    const int g = (bid - 256) * 256 + t;  // 0..32767
    const int c = g >> 6, d = g & 63;     // lanes d-contiguous -> coalesced Wqkv reads
    float s = 0.f;
#pragma unroll
    for (int h = 0; h < 8; ++h) s += Wqkv[(size_t)c * 1536 + 1024 + h * 64 + d];
    Wvt[(size_t)d * 512 + c] = __float2bfloat16(s * 0.125f);
    if (g < 64) {
      float sb = 0.f;
#pragma unroll
      for (int h = 0; h < 8; ++h) sb += bqkv[1024 + h * 64 + d];
      bv[d] = sb * 0.125f;
    }
  }
}

// gemm1: grid (16 nt, 32 b), 256 thr (4 waves, 2x2 wave tiles of 32n x 32d).
// Block tile 64n x 64d, BK=64. X: fp32 global -> bf16 transpose-pack -> swizzled LDS.
// Wvt: global_load_lds with pre-swizzled source. One barrier per K-chunk.
__global__ __launch_bounds__(256) void gemm1_kernel(
    const float* __restrict__ x, const __hip_bfloat16* __restrict__ Wvt,
    const float* __restrict__ bv, __hip_bfloat16* __restrict__ V) {
  __shared__ __hip_bfloat16 Xl[2][4096];  // [n64][c64], granule swizzle (n>>1)&7
  __shared__ __hip_bfloat16 Wl[2][4096];  // [d64][c64], granule swizzle d&7
  const int nt = blockIdx.x, b = blockIdx.y;
  const int t = (int)threadIdx.x, w = t >> 6, lane = t & 63;
  const int wr = w >> 1, wc = w & 1;
  const int cq = t >> 4, nq = t & 15;  // staging: c-quad, n-quad
  const float* xg = x + (size_t)b * 524288 + (size_t)nt * 64 + nq * 4;

  float4 xr[4];
#define XLOAD(kc)                                                            \
  do {                                                                       \
    _Pragma("unroll") for (int r = 0; r < 4; ++r)                            \
        xr[r] = *(const float4*)(xg + (size_t)((kc) * 64 + cq * 4 + r) * 1024); \
  } while (0)
#define XWRITE(buf)                                                          \
  do {                                                                       \
    _Pragma("unroll") for (int jn = 0; jn < 4; ++jn) {                       \
      int n = nq * 4 + jn;                                                   \
      u32 lo = packbf2(((const float*)&xr[0])[jn], ((const float*)&xr[1])[jn]); \
      u32 hi = packbf2(((const float*)&xr[2])[jn], ((const float*)&xr[3])[jn]); \
      int byte = (n * 128 + cq * 8) ^ (((n >> 1) & 7) << 4);                 \
      *(uint2*)((char*)&Xl[buf][0] + byte) = make_uint2(lo, hi);             \
    }                                                                        \
  } while (0)
#define WSTAGE(buf, kc)                                                      \
  do {                                                                       \
    _Pragma("unroll") for (int q = 0; q < 2; ++q) {                          \
      int g = w * 128 + q * 64 + lane;                                       \
      int r = g >> 3, ww = g & 7;                                            \
      gll16(Wvt + (size_t)r * 512 + (kc) * 64 + ((ww ^ (r & 7)) << 3),       \
            (char*)&Wl[buf][0] + (w * 128 + q * 64) * 16);                   \
    }                                                                        \
  } while (0)

  f32x4 acc[2][2] = {{{0.f, 0.f, 0.f, 0.f}, {0.f, 0.f, 0.f, 0.f}},
                     {{0.f, 0.f, 0.f, 0.f}, {0.f, 0.f, 0.f, 0.f}}};
  XLOAD(0);
  WSTAGE(0, 0);
  XWRITE(0);
  __syncthreads();
  for (int kc = 0; kc < 8; ++kc) {
    const int cur = kc & 1;
    if (kc < 7) {
      XLOAD(kc + 1);
      WSTAGE(cur ^ 1, kc + 1);
    }
    const char* Xb = (const char*)&Xl[cur][0];
    const char* Wb = (const char*)&Wl[cur][0];
#pragma unroll
    for (int kb = 0; kb < 2; ++kb) {
      short8 af[2], bf[2];
#pragma unroll
      for (int mi = 0; mi < 2; ++mi) {
        int n = wr * 32 + mi * 16 + (lane & 15);
        int gc = (kb * 4 + (lane >> 4)) ^ ((n >> 1) & 7);
        af[mi] = *(const short8*)(Xb + n * 128 + gc * 16);
      }
#pragma unroll
      for (int ni = 0; ni < 2; ++ni) {
        int d = wc * 32 + ni * 16 + (lane & 15);
        int gc = (kb * 4 + (lane >> 4)) ^ (d & 7);
        bf[ni] = *(const short8*)(Wb + d * 128 + gc * 16);
      }
#pragma unroll
      for (int mi = 0; mi < 2; ++mi)
#pragma unroll
        for (int ni = 0; ni < 2; ++ni)
          acc[mi][ni] = __builtin_amdgcn_mfma_f32_16x16x32_bf16(af[mi], bf[ni], acc[mi][ni], 0, 0, 0);
    }
    if (kc < 7) XWRITE(cur ^ 1);
    __syncthreads();
  }
#undef XLOAD
#undef XWRITE
#undef WSTAGE
  // Epilogue: D col(lane&15)=d, rows=(lane>>4)*4+reg = n. +bv, bf16 store.
#pragma unroll
  for (int ni = 0; ni < 2; ++ni) {
    const int d = wc * 32 + ni * 16 + (lane & 15);
    const float bvd = bv[d];
#pragma unroll
    for (int mi = 0; mi < 2; ++mi) {
      const int n0 = nt * 64 + wr * 32 + mi * 16 + (lane >> 4) * 4;
#pragma unroll
      for (int r = 0; r < 4; ++r)
        V[((size_t)b * 1024 + n0 + r) * 64 + d] = __float2bfloat16(acc[mi][ni][r] + bvd);
    }
  }
}

// gemm2: 512 blocks (XCD-chunked), 256 thr. Tile 64j x 64c', BK=64.
// Z (=V bf16) and Wpt staged via global_load_lds, pre-swizzled source (r&7).
// Epilogue: P -> stride-65 LDS -> 8x-replicated coalesced dwordx4 stores.
__global__ __launch_bounds__(256) void gemm2_kernel(
    const __hip_bfloat16* __restrict__ Vb, const __hip_bfloat16* __restrict__ Wpt,
    const float* __restrict__ bproj, float* __restrict__ out) {
  __shared__ char smem[32768];  // Zl[2][8KB] | Wl[2][8KB]; Pl(16640B) aliases at 0
  char* Zl0 = smem;
  char* Wl0 = smem + 16384;
  const int lin = (((int)blockIdx.x & 7) << 6) | ((int)blockIdx.x >> 3);  // XCD chunking
  const int ct = lin & 7, jt = (lin >> 3) & 1, b = lin >> 4;
  const int t = (int)threadIdx.x, w = t >> 6, lane = t & 63;
  const int wr = w >> 1, wc = w & 1;
  const __hip_bfloat16* Zg = Vb + (size_t)b * 65536 + (size_t)jt * 64 * 512;
  const __hip_bfloat16* Wg = Wpt + (size_t)ct * 64 * 512;

#define STAGE(buf, kc)                                                       \
  do {                                                                       \
    _Pragma("unroll") for (int q = 0; q < 2; ++q) {                          \
      int g = w * 128 + q * 64 + lane;                                       \
      int r = g >> 3, ww = g & 7;                                            \
      int cof = (kc) * 64 + ((ww ^ (r & 7)) << 3);                           \
      int ldsoff = (w * 128 + q * 64) * 16;                                  \
      gll16(Zg + (size_t)r * 512 + cof, Zl0 + (buf) * 8192 + ldsoff);        \
      gll16(Wg + (size_t)r * 512 + cof, Wl0 + (buf) * 8192 + ldsoff);        \
    }                                                                        \
  } while (0)

  f32x4 acc[2][2] = {{{0.f, 0.f, 0.f, 0.f}, {0.f, 0.f, 0.f, 0.f}},
                     {{0.f, 0.f, 0.f, 0.f}, {0.f, 0.f, 0.f, 0.f}}};
  STAGE(0, 0);
  __syncthreads();
  for (int kc = 0; kc < 8; ++kc) {
    const int cur = kc & 1;
    if (kc < 7) STAGE(cur ^ 1, kc + 1);
    const char* Zb = Zl0 + cur * 8192;
    const char* Wb = Wl0 + cur * 8192;
#pragma unroll
    for (int kb = 0; kb < 2; ++kb) {
      short8 af[2], bf[2];
#pragma unroll
      for (int mi = 0; mi < 2; ++mi) {
        int j = wr * 32 + mi * 16 + (lane & 15);
        int gc = (kb * 4 + (lane >> 4)) ^ (j & 7);
        af[mi] = *(const short8*)(Zb + j * 128 + gc * 16);
      }
#pragma unroll
      for (int ni = 0; ni < 2; ++ni) {
        int p = wc * 32 + ni * 16 + (lane & 15);
        int gc = (kb * 4 + (lane >> 4)) ^ (p & 7);
        bf[ni] = *(const short8*)(Wb + p * 128 + gc * 16);
      }
#pragma unroll
      for (int mi = 0; mi < 2; ++mi)
#pragma unroll
        for (int ni = 0; ni < 2; ++ni)
          acc[mi][ni] = __builtin_amdgcn_mfma_f32_16x16x32_bf16(af[mi], bf[ni], acc[mi][ni], 0, 0, 0);
    }
    __syncthreads();
  }
#undef STAGE
  // P tile (+bproj) -> LDS [64][65] f32
  float* Pl = (float*)smem;
#pragma unroll
  for (int ni = 0; ni < 2; ++ni) {
    const int p = wc * 32 + ni * 16 + (lane & 15);
    const float bp = bproj[ct * 64 + p];
#pragma unroll
    for (int mi = 0; mi < 2; ++mi) {
      const int j0 = wr * 32 + mi * 16 + (lane >> 4) * 4;
#pragma unroll
      for (int r = 0; r < 4; ++r) Pl[(j0 + r) * 65 + p] = acc[mi][ni][r] + bp;
    }
  }
  __syncthreads();
  // out[b][ct*64+cl][rep*128 + jt*64 + j] ; 8192 float4 per block
  float* ob = out + ((size_t)b * 512 + ct * 64) * 1024 + jt * 64;
#pragma unroll 8
  for (int k = 0; k < 32; ++k) {
    int F = t + 256 * k;
    int cl = F >> 7;
    int rem = F & 127;
    int rep = rem >> 4;
    int j4 = (rem & 15) * 4;
    float4 v;
    v.x = Pl[(j4 + 0) * 65 + cl];
    v.y = Pl[(j4 + 1) * 65 + cl];
    v.z = Pl[(j4 + 2) * 65 + cl];
    v.w = Pl[(j4 + 3) * 65 + cl];
    *(float4*)(ob + (size_t)cl * 1024 + rep * 128 + j4) = v;
  }
}

extern "C" void kernel_launch(void* const* d_in, const int* in_sizes, int n_in,
                              void* d_out, int out_size, void* d_ws, size_t ws_size,
                              hipStream_t stream) {
  (void)in_sizes; (void)n_in; (void)out_size; (void)ws_size;
  const float* x     = (const float*)d_in[0];
  const float* Wqkv  = (const float*)d_in[1];
  const float* bqkv  = (const float*)d_in[2];
  const float* Wproj = (const float*)d_in[3];
  const float* bproj = (const float*)d_in[4];
  float* out = (float*)d_out;
  char* ws = (char*)d_ws;
  __hip_bfloat16* Wvt = (__hip_bfloat16*)(ws);            // 64*512*2   = 65536 B
  __hip_bfloat16* Wpt = (__hip_bfloat16*)(ws + 65536);    // 512*512*2  = 524288 B
  float*          bv  = (float*)(ws + 589824);            // 256 B
  __hip_bfloat16* Vb  = (__hip_bfloat16*)(ws + 590080);   // 32*1024*64*2 = 4 MiB

  prep_kernel<<<384, 256, 0, stream>>>(Wqkv, bqkv, Wproj, Wvt, bv, Wpt);
  gemm1_kernel<<<dim3(16, 32), 256, 0, stream>>>(x, Wvt, bv, Vb);
  gemm2_kernel<<<512, 256, 0, stream>>>(Vb, Wpt, bproj, out);
}